// Round 6
// baseline (1846.019 us; speedup 1.0000x reference)
//
#include <hip/hip_runtime.h>
#include <hip/hip_fp16.h>

#define TPB 256
#define EPT 16            // edges per thread in scatter_buckets
#define BNODES 4096       // nodes per coarse bucket (12 low bits)

typedef unsigned int uv4 __attribute__((ext_vector_type(4)));
typedef float        fv4 __attribute__((ext_vector_type(4)));

// ---------------- coarse histogram of dst >> 12 ----------------
__global__ void hist_buckets(const int* __restrict__ dst, int* __restrict__ hist, int nE) {
    __shared__ int lh[256];
    lh[threadIdx.x] = 0;
    __syncthreads();
    int stride = gridDim.x * blockDim.x;
    for (int e = blockIdx.x * blockDim.x + threadIdx.x; e < nE; e += stride)
        atomicAdd(&lh[dst[e] >> 12], 1);
    __syncthreads();
    if (lh[threadIdx.x]) atomicAdd(&hist[threadIdx.x], lh[threadIdx.x]);
}

// ---------------- exclusive scan of 256 bucket counts ----------------
__global__ void scan256(const int* __restrict__ hist, int* __restrict__ bucketOff,
                        int* __restrict__ tails, int nE) {
    __shared__ int lds[256];
    int t = threadIdx.x;
    int v = hist[t];
    lds[t] = v;
    __syncthreads();
    for (int off = 1; off < 256; off <<= 1) {
        int u = (t >= off) ? lds[t - off] : 0;
        __syncthreads();
        lds[t] += u;
        __syncthreads();
    }
    int excl = lds[t] - v;
    bucketOff[t] = excl;
    tails[t] = excl;
    if (t == 255) bucketOff[256] = lds[255];   // == nE
}

// ---------------- scatter edges into coarse buckets (block-aggregated) ----------------
// payload: (dstLow12 << 20) | src   (requires n <= 2^20)
__global__ void scatter_buckets(const int* __restrict__ src, const int* __restrict__ dst,
                                int* __restrict__ tails, unsigned* __restrict__ bucketData,
                                int nE) {
    __shared__ int hist[256];
    __shared__ int cbase[256];
    int t = threadIdx.x;
    hist[t] = 0;
    __syncthreads();
    long base = (long)blockIdx.x * (TPB * EPT);
    int bk[EPT];
    int lo[EPT];
#pragma unroll
    for (int j = 0; j < EPT; ++j) {
        long e = base + t + (long)j * TPB;
        if (e < nE) {
            int d = dst[e];
            bk[j] = d >> 12;
            lo[j] = d & 4095;
            atomicAdd(&hist[bk[j]], 1);
        } else bk[j] = -1;
    }
    __syncthreads();
    int h = hist[t];
    cbase[t] = (h > 0) ? atomicAdd(&tails[t], h) : 0;
    __syncthreads();
    hist[t] = 0;   // reuse as block-local cursor
    __syncthreads();
#pragma unroll
    for (int j = 0; j < EPT; ++j) {
        long e = base + t + (long)j * TPB;
        if (bk[j] >= 0) {
            int r = atomicAdd(&hist[bk[j]], 1);
            unsigned s = (unsigned)src[e];
            bucketData[cbase[bk[j]] + r] = ((unsigned)lo[j] << 20) | s;
        }
    }
}

// ---------------- per-bucket: degrees -> dis, rowptr (scan), col (contiguous, src-sorted rows) ----------------
__global__ void build_csr(const unsigned* __restrict__ bucketData,
                          const int* __restrict__ bucketOff,
                          int* __restrict__ rowptr, int* __restrict__ col,
                          float* __restrict__ dis, int n, int nE) {
    __shared__ int cnt[BNODES];     // 16 KB
    __shared__ int partial[TPB];
    int b = blockIdx.x;
    int t = threadIdx.x;
    for (int j = t; j < BNODES; j += TPB) cnt[j] = 0;
    __syncthreads();
    int e0 = bucketOff[b], e1 = bucketOff[b + 1];
    // count pass
    for (int k = e0 + t; k < e1; k += TPB)
        atomicAdd(&cnt[bucketData[k] >> 20], 1);
    __syncthreads();
    // dis from degree
    int base0 = b << 12;
    for (int j = t; j < BNODES; j += TPB) {
        int node = base0 + j;
        if (node < n) dis[node] = rsqrtf((float)cnt[j] + 1.0f);
    }
    // exclusive scan of cnt[0..4095]: serial-16 per thread + block scan of partials
    int tb = t * 16;
    int loc[16];
    int s = 0;
#pragma unroll
    for (int j = 0; j < 16; ++j) { loc[j] = s; s += cnt[tb + j]; }
    partial[t] = s;
    __syncthreads();
    for (int off = 1; off < TPB; off <<= 1) {
        int u = (t >= off) ? partial[t - off] : 0;
        __syncthreads();
        partial[t] += u;
        __syncthreads();
    }
    int pbase = (t > 0) ? partial[t - 1] : 0;
    __syncthreads();
    // write rowptr; convert cnt to global cursor
#pragma unroll
    for (int j = 0; j < 16; ++j) {
        int node = base0 + tb + j;
        int gbase = e0 + pbase + loc[j];
        cnt[tb + j] = gbase;
        if (node < n) rowptr[node] = gbase;
    }
    if (b == 0 && t == 0) rowptr[n] = nE;
    __syncthreads();
    // scatter pass: col writes land in [e0, e1) — contiguous, L2-resident
    for (int k = e0 + t; k < e1; k += TPB) {
        unsigned p = bucketData[k];
        int pos = atomicAdd(&cnt[p >> 20], 1);
        col[pos] = (int)(p & 0xFFFFFu);
    }
    __syncthreads();
    // sort each row ascending by src (insertion sort; rows avg ~10 long).
    // Sorted rows => all pull threads sweep src space in order => gathers
    // concentrate in a moving band that fits per-XCD L2.
#pragma unroll
    for (int j = 0; j < 16; ++j) {
        int node = base0 + tb + j;
        if (node >= n) continue;
        int rs = e0 + pbase + loc[j];   // row start (regs still live)
        int re = cnt[tb + j];           // row end (cursor after scatter)
        for (int a = rs + 1; a < re; ++a) {
            int v = col[a];
            int c = a - 1;
            while (c >= rs && col[c] > v) { col[c + 1] = col[c]; --c; }
            col[c + 1] = v;
        }
    }
}

union H8 { uv4 u; __half2 h2[4]; };

// ---------------- layer 1 node kernel: hs = (x*W1)*dis  (fp16x8) ----------------
__global__ void node_l1(const float* __restrict__ x, const float* __restrict__ W1,
                        const float* __restrict__ dis, __half* __restrict__ hs, int n) {
    int i = blockIdx.x * blockDim.x + threadIdx.x;
    if (i >= n) return;
    float xd = x[i] * dis[i];
    float4 w0 = ((const float4*)W1)[0];
    float4 w1 = ((const float4*)W1)[1];
    H8 o;
    o.h2[0] = __floats2half2_rn(xd * w0.x, xd * w0.y);
    o.h2[1] = __floats2half2_rn(xd * w0.z, xd * w0.w);
    o.h2[2] = __floats2half2_rn(xd * w1.x, xd * w1.y);
    o.h2[3] = __floats2half2_rn(xd * w1.z, xd * w1.w);
    ((uv4*)hs)[i] = o.u;
}

// ---------------- fused pull + node transform (layers 1..3 boundaries) ----------------
// g = dis[i]*(sum hs_in[c] + hs_in[i]);  t = relu(g + b);  hs_out = (t @ W) * dis[i]
// Streams (col/rowptr/dis/out) are non-temporal so the gather band stays in L2.
__global__ void pull_mid(const int* __restrict__ rowptr, const int* __restrict__ col,
                         const float* __restrict__ dis, const __half* __restrict__ hs_in,
                         const float* __restrict__ bias, const float* __restrict__ W,
                         __half* __restrict__ hs_out, int n) {
    int i = blockIdx.x * blockDim.x + threadIdx.x;
    if (i >= n) return;
    const uv4* hv = (const uv4*)hs_in;
    H8 p; p.u = hv[i];                       // self term (cached)
    float2 a0 = __half22float2(p.h2[0]);
    float2 a1 = __half22float2(p.h2[1]);
    float2 a2 = __half22float2(p.h2[2]);
    float2 a3 = __half22float2(p.h2[3]);
    int s = __builtin_nontemporal_load(&rowptr[i]);
    int e = __builtin_nontemporal_load(&rowptr[i + 1]);
    for (int k = s; k < e; ++k) {
        int c = __builtin_nontemporal_load(&col[k]);
        H8 q; q.u = hv[c];
        float2 b0 = __half22float2(q.h2[0]);
        float2 b1 = __half22float2(q.h2[1]);
        float2 b2 = __half22float2(q.h2[2]);
        float2 b3 = __half22float2(q.h2[3]);
        a0.x += b0.x; a0.y += b0.y; a1.x += b1.x; a1.y += b1.y;
        a2.x += b2.x; a2.y += b2.y; a3.x += b3.x; a3.y += b3.y;
    }
    float d = __builtin_nontemporal_load(&dis[i]);
    float t[8] = {a0.x * d, a0.y * d, a1.x * d, a1.y * d,
                  a2.x * d, a2.y * d, a3.x * d, a3.y * d};
#pragma unroll
    for (int k = 0; k < 8; ++k) {
        float v = t[k] + bias[k];
        t[k] = v > 0.0f ? v : 0.0f;
    }
    float h[8];
#pragma unroll
    for (int j = 0; j < 8; ++j) {
        float acc = 0.0f;
#pragma unroll
        for (int k = 0; k < 8; ++k) acc += t[k] * W[k * 8 + j];
        h[j] = acc * d;
    }
    H8 o;
    o.h2[0] = __floats2half2_rn(h[0], h[1]);
    o.h2[1] = __floats2half2_rn(h[2], h[3]);
    o.h2[2] = __floats2half2_rn(h[4], h[5]);
    o.h2[3] = __floats2half2_rn(h[6], h[7]);
    __builtin_nontemporal_store(o.u, &((uv4*)hs_out)[i]);
}

// ---------------- final pull: g = dis[i]*(sum + self), fp32 out ----------------
__global__ void pull_last(const int* __restrict__ rowptr, const int* __restrict__ col,
                          const float* __restrict__ dis, const __half* __restrict__ hs_in,
                          float* __restrict__ g, int n) {
    int i = blockIdx.x * blockDim.x + threadIdx.x;
    if (i >= n) return;
    const uv4* hv = (const uv4*)hs_in;
    H8 p; p.u = hv[i];
    float2 a0 = __half22float2(p.h2[0]);
    float2 a1 = __half22float2(p.h2[1]);
    float2 a2 = __half22float2(p.h2[2]);
    float2 a3 = __half22float2(p.h2[3]);
    int s = __builtin_nontemporal_load(&rowptr[i]);
    int e = __builtin_nontemporal_load(&rowptr[i + 1]);
    for (int k = s; k < e; ++k) {
        int c = __builtin_nontemporal_load(&col[k]);
        H8 q; q.u = hv[c];
        float2 b0 = __half22float2(q.h2[0]);
        float2 b1 = __half22float2(q.h2[1]);
        float2 b2 = __half22float2(q.h2[2]);
        float2 b3 = __half22float2(q.h2[3]);
        a0.x += b0.x; a0.y += b0.y; a1.x += b1.x; a1.y += b1.y;
        a2.x += b2.x; a2.y += b2.y; a3.x += b3.x; a3.y += b3.y;
    }
    float d = __builtin_nontemporal_load(&dis[i]);
    fv4* gp = (fv4*)(g + (size_t)i * 8);
    fv4 o0 = {a0.x * d, a0.y * d, a1.x * d, a1.y * d};
    fv4 o1 = {a2.x * d, a2.y * d, a3.x * d, a3.y * d};
    __builtin_nontemporal_store(o0, gp);
    __builtin_nontemporal_store(o1, gp + 1);
}

// ---------------- final gather: out[i][:] = g[idx[i]][:] + b4 ----------------
__global__ void gather_out(const float* __restrict__ g, const int* __restrict__ idx,
                           const float* __restrict__ b, float* __restrict__ out, int B) {
    int t = blockIdx.x * blockDim.x + threadIdx.x;
    if (t >= B * 8) return;
    int i = t >> 3, j = t & 7;
    out[t] = g[(size_t)idx[i] * 8 + j] + b[j];
}

extern "C" void kernel_launch(void* const* d_in, const int* in_sizes, int n_in,
                              void* d_out, int out_size, void* d_ws, size_t ws_size,
                              hipStream_t stream) {
    const float* x   = (const float*)d_in[0];
    const int*   ei  = (const int*)d_in[1];
    const int*   idx = (const int*)d_in[2];
    const float* W1  = (const float*)d_in[3];
    const float* b1  = (const float*)d_in[4];
    const float* W2  = (const float*)d_in[5];
    const float* b2  = (const float*)d_in[6];
    const float* W3  = (const float*)d_in[7];
    const float* b3  = (const float*)d_in[8];
    const float* W4  = (const float*)d_in[9];
    const float* b4  = (const float*)d_in[10];

    const int n = in_sizes[0];      // 1,000,000 nodes (requires n <= 2^20 for packing)
    const int E = in_sizes[1] / 2;  // 10,000,000 edges
    const int B = in_sizes[2];      // 64 graphs

    const int* src = ei;
    const int* dst = ei + E;

    // workspace layout (int elements; all float4/uint4 regions 16B-aligned):
    //   rowptr: n+4 | col: E | dis: n | hs_a: 4n (fp16x8) | hs_b: 4n | g: 8n | small
    //   bucketData (E unsigned) aliases hs_b+g (consumed in build_csr before writes)
    size_t o_rowptr = 0;
    size_t o_col    = o_rowptr + ((size_t)n + 4);
    size_t o_dis    = o_col    + (size_t)E;
    size_t o_hsa    = o_dis    + (size_t)n;
    size_t o_hsb    = o_hsa    + (size_t)n * 4;
    size_t o_g      = o_hsb    + (size_t)n * 4;
    size_t o_small  = o_g      + (size_t)n * 8;

    int*      rowptr     = (int*)d_ws + o_rowptr;
    int*      col        = (int*)d_ws + o_col;
    float*    dis        = (float*)d_ws + o_dis;
    __half*   hs_a       = (__half*)((int*)d_ws + o_hsa);
    __half*   hs_b       = (__half*)((int*)d_ws + o_hsb);
    float*    g          = (float*)d_ws + o_g;
    int*      hist       = (int*)d_ws + o_small;
    int*      bucketOff  = hist + 256;
    int*      tails      = bucketOff + 260;
    unsigned* bucketData = (unsigned*)hs_b;   // alias: 40 MB over hs_b(16MB)+g head

    const int NB = (n + BNODES - 1) / BNODES;   // coarse buckets (<= 256)
    const int gn = (n + TPB - 1) / TPB;
    const int gs = (int)(((long)E + TPB * EPT - 1) / (TPB * EPT));

    // ---- build CSR ----
    (void)hipMemsetAsync(hist, 0, 256 * sizeof(int), stream);
    hist_buckets<<<1024, TPB, 0, stream>>>(dst, hist, E);
    scan256<<<1, 256, 0, stream>>>(hist, bucketOff, tails, E);
    scatter_buckets<<<gs, TPB, 0, stream>>>(src, dst, tails, bucketData, E);
    build_csr<<<NB, TPB, 0, stream>>>(bucketData, bucketOff, rowptr, col, dis, n, E);

    // ---- 4 GCN layers: fused pull + node transform ----
    node_l1<<<gn, TPB, 0, stream>>>(x, W1, dis, hs_a, n);
    pull_mid<<<gn, TPB, 0, stream>>>(rowptr, col, dis, hs_a, b1, W2, hs_b, n);
    pull_mid<<<gn, TPB, 0, stream>>>(rowptr, col, dis, hs_b, b2, W3, hs_a, n);
    pull_mid<<<gn, TPB, 0, stream>>>(rowptr, col, dis, hs_a, b3, W4, hs_b, n);
    pull_last<<<gn, TPB, 0, stream>>>(rowptr, col, dis, hs_b, g, n);

    gather_out<<<(B * 8 + TPB - 1) / TPB, TPB, 0, stream>>>(g, idx, b4, (float*)d_out, B);
}

// Round 7
// 1354.391 us; speedup vs baseline: 1.3630x; 1.3630x over previous
//
#include <hip/hip_runtime.h>
#include <hip/hip_fp16.h>

#define TPB 256
#define BN 1024           // nodes per coarse bucket (10 low bits)
#define ESTAGE 11264      // LDS staging capacity (mean 10240 + 10 sigma)
#define SCHUNK 16384      // edges per block in scatter_buckets

typedef unsigned int uv4 __attribute__((ext_vector_type(4)));
typedef float        fv4 __attribute__((ext_vector_type(4)));

// ---------------- coarse histogram of dst >> 10 ----------------
__global__ void hist_buckets(const int* __restrict__ dst, int* __restrict__ hist, int nE) {
    __shared__ int lh[BN];
    for (int j = threadIdx.x; j < BN; j += blockDim.x) lh[j] = 0;
    __syncthreads();
    int stride = gridDim.x * blockDim.x;
    for (int e = blockIdx.x * blockDim.x + threadIdx.x; e < nE; e += stride)
        atomicAdd(&lh[dst[e] >> 10], 1);
    __syncthreads();
    for (int j = threadIdx.x; j < BN; j += blockDim.x)
        if (lh[j]) atomicAdd(&hist[j], lh[j]);
}

// ---------------- exclusive scan of 1024 bucket counts ----------------
__global__ void scan1024(const int* __restrict__ hist, int* __restrict__ bucketOff,
                         int* __restrict__ tails, int nE) {
    __shared__ int lds[BN];
    int t = threadIdx.x;
    int v = hist[t];
    lds[t] = v;
    __syncthreads();
    for (int off = 1; off < BN; off <<= 1) {
        int u = (t >= off) ? lds[t - off] : 0;
        __syncthreads();
        lds[t] += u;
        __syncthreads();
    }
    int excl = lds[t] - v;
    bucketOff[t] = excl;
    tails[t] = excl;
    if (t == BN - 1) bucketOff[BN] = lds[BN - 1];   // == nE
}

// ---------------- scatter edges into coarse buckets (two-pass, block-aggregated) ----------
// payload: (dstLow10 << 20) | src   (requires n <= 2^20)
__global__ void scatter_buckets(const int* __restrict__ src, const int* __restrict__ dst,
                                int* __restrict__ tails, unsigned* __restrict__ bucketData,
                                int nE) {
    __shared__ int hist[BN];
    __shared__ int cbase[BN];
    int t = threadIdx.x;
    long base = (long)blockIdx.x * SCHUNK;
    int m = (int)(((long)nE - base < SCHUNK) ? (nE - base) : SCHUNK);
    for (int j = t; j < BN; j += TPB) hist[j] = 0;
    __syncthreads();
    // pass 1: count
    for (int k = t; k < m; k += TPB)
        atomicAdd(&hist[dst[base + k] >> 10], 1);
    __syncthreads();
    // reserve contiguous runs per bucket
    for (int j = t; j < BN; j += TPB) {
        int h = hist[j];
        cbase[j] = h ? atomicAdd(&tails[j], h) : 0;
    }
    __syncthreads();
    for (int j = t; j < BN; j += TPB) hist[j] = 0;   // reuse as cursor
    __syncthreads();
    // pass 2: scatter
    for (int k = t; k < m; k += TPB) {
        int d = dst[base + k];
        int b = d >> 10;
        int r = atomicAdd(&hist[b], 1);
        bucketData[cbase[b] + r] = ((unsigned)(d & (BN - 1)) << 20) | (unsigned)src[base + k];
    }
}

// ---------------- per-bucket: degrees -> dis, rowptr, row-grouped + src-sorted col ------
// All grouping and sorting happens in LDS; col write-out is coalesced.
__global__ __launch_bounds__(TPB) void build_csr(
        const unsigned* __restrict__ bucketData, const int* __restrict__ bucketOff,
        int* __restrict__ rowptr, int* __restrict__ col,
        float* __restrict__ dis, int n, int nE) {
    __shared__ unsigned sorted[ESTAGE];   // 44 KB
    __shared__ int cnt[BN];               // 4 KB
    __shared__ int partial[TPB];
    int b = blockIdx.x;
    int t = threadIdx.x;
    int e0 = bucketOff[b], e1 = bucketOff[b + 1];
    int m = e1 - e0;
    for (int j = t; j < BN; j += TPB) cnt[j] = 0;
    __syncthreads();
    // count pass (global read #1)
    for (int k = e0 + t; k < e1; k += TPB)
        atomicAdd(&cnt[bucketData[k] >> 20], 1);
    __syncthreads();
    // dis from degree
    int base0 = b << 10;
    for (int j = t; j < BN; j += TPB) {
        int node = base0 + j;
        if (node < n) dis[node] = rsqrtf((float)cnt[j] + 1.0f);
    }
    // exclusive scan of cnt[0..1023]: serial-4 per thread + block scan of partials
    int tb = t * 4;
    int loc[4];
    int s = 0;
#pragma unroll
    for (int j = 0; j < 4; ++j) { loc[j] = s; s += cnt[tb + j]; }
    partial[t] = s;
    __syncthreads();
    for (int off = 1; off < TPB; off <<= 1) {
        int u = (t >= off) ? partial[t - off] : 0;
        __syncthreads();
        partial[t] += u;
        __syncthreads();
    }
    int pbase = (t > 0) ? partial[t - 1] : 0;
    __syncthreads();
    // rowptr + local cursors
#pragma unroll
    for (int j = 0; j < 4; ++j) {
        int node = base0 + tb + j;
        int lb = pbase + loc[j];
        cnt[tb + j] = lb;                  // local row start (cursor)
        if (node < n) rowptr[node] = e0 + lb;
    }
    if (b == 0 && t == 0) rowptr[n] = nE;
    __syncthreads();
    if (m <= ESTAGE) {
        // scatter into LDS, row-grouped (global read #2)
        for (int k = e0 + t; k < e1; k += TPB) {
            unsigned p = bucketData[k];
            int pos = atomicAdd(&cnt[p >> 20], 1);
            sorted[pos] = p;
        }
        __syncthreads();
        // insertion-sort each row in LDS (dst constant within row => sorts by src)
        for (int j = t; j < BN; j += TPB) {
            int rs = (j == 0) ? 0 : cnt[j - 1];
            int re = cnt[j];
            for (int a = rs + 1; a < re; ++a) {
                unsigned v = sorted[a];
                int c = a - 1;
                while (c >= rs && sorted[c] > v) { sorted[c + 1] = sorted[c]; --c; }
                sorted[c + 1] = v;
            }
        }
        __syncthreads();
        // coalesced write-out
        for (int k = t; k < m; k += TPB)
            col[e0 + k] = (int)(sorted[k] & 0xFFFFFu);
    } else {
        // fallback (statistically never): global scatter + global per-row sort
        for (int k = e0 + t; k < e1; k += TPB) {
            unsigned p = bucketData[k];
            int pos = atomicAdd(&cnt[p >> 20], 1);
            col[e0 + pos] = (int)(p & 0xFFFFFu);
        }
        __syncthreads();
        for (int j = t; j < BN; j += TPB) {
            int rs = e0 + ((j == 0) ? 0 : cnt[j - 1]);
            int re = e0 + cnt[j];
            for (int a = rs + 1; a < re; ++a) {
                int v = col[a];
                int c = a - 1;
                while (c >= rs && col[c] > v) { col[c + 1] = col[c]; --c; }
                col[c + 1] = v;
            }
        }
    }
}

union H8 { uv4 u; __half2 h2[4]; };

// ---------------- layer 1 node kernel: hs = (x*W1)*dis  (fp16x8) ----------------
__global__ void node_l1(const float* __restrict__ x, const float* __restrict__ W1,
                        const float* __restrict__ dis, __half* __restrict__ hs, int n) {
    int i = blockIdx.x * blockDim.x + threadIdx.x;
    if (i >= n) return;
    float xd = x[i] * dis[i];
    float4 w0 = ((const float4*)W1)[0];
    float4 w1 = ((const float4*)W1)[1];
    H8 o;
    o.h2[0] = __floats2half2_rn(xd * w0.x, xd * w0.y);
    o.h2[1] = __floats2half2_rn(xd * w0.z, xd * w0.w);
    o.h2[2] = __floats2half2_rn(xd * w1.x, xd * w1.y);
    o.h2[3] = __floats2half2_rn(xd * w1.z, xd * w1.w);
    ((uv4*)hs)[i] = o.u;
}

// ---------------- fused pull + node transform (layers 1..3 boundaries) ----------------
__global__ void pull_mid(const int* __restrict__ rowptr, const int* __restrict__ col,
                         const float* __restrict__ dis, const __half* __restrict__ hs_in,
                         const float* __restrict__ bias, const float* __restrict__ W,
                         __half* __restrict__ hs_out, int n) {
    int i = blockIdx.x * blockDim.x + threadIdx.x;
    if (i >= n) return;
    const uv4* hv = (const uv4*)hs_in;
    H8 p; p.u = hv[i];                       // self term (cached)
    float2 a0 = __half22float2(p.h2[0]);
    float2 a1 = __half22float2(p.h2[1]);
    float2 a2 = __half22float2(p.h2[2]);
    float2 a3 = __half22float2(p.h2[3]);
    int s = __builtin_nontemporal_load(&rowptr[i]);
    int e = __builtin_nontemporal_load(&rowptr[i + 1]);
    for (int k = s; k < e; ++k) {
        int c = __builtin_nontemporal_load(&col[k]);
        H8 q; q.u = hv[c];
        float2 b0 = __half22float2(q.h2[0]);
        float2 b1 = __half22float2(q.h2[1]);
        float2 b2 = __half22float2(q.h2[2]);
        float2 b3 = __half22float2(q.h2[3]);
        a0.x += b0.x; a0.y += b0.y; a1.x += b1.x; a1.y += b1.y;
        a2.x += b2.x; a2.y += b2.y; a3.x += b3.x; a3.y += b3.y;
    }
    float d = __builtin_nontemporal_load(&dis[i]);
    float t[8] = {a0.x * d, a0.y * d, a1.x * d, a1.y * d,
                  a2.x * d, a2.y * d, a3.x * d, a3.y * d};
#pragma unroll
    for (int k = 0; k < 8; ++k) {
        float v = t[k] + bias[k];
        t[k] = v > 0.0f ? v : 0.0f;
    }
    float h[8];
#pragma unroll
    for (int j = 0; j < 8; ++j) {
        float acc = 0.0f;
#pragma unroll
        for (int k = 0; k < 8; ++k) acc += t[k] * W[k * 8 + j];
        h[j] = acc * d;
    }
    H8 o;
    o.h2[0] = __floats2half2_rn(h[0], h[1]);
    o.h2[1] = __floats2half2_rn(h[2], h[3]);
    o.h2[2] = __floats2half2_rn(h[4], h[5]);
    o.h2[3] = __floats2half2_rn(h[6], h[7]);
    __builtin_nontemporal_store(o.u, &((uv4*)hs_out)[i]);
}

// ---------------- final pull: g = dis[i]*(sum + self), fp32 out ----------------
__global__ void pull_last(const int* __restrict__ rowptr, const int* __restrict__ col,
                          const float* __restrict__ dis, const __half* __restrict__ hs_in,
                          float* __restrict__ g, int n) {
    int i = blockIdx.x * blockDim.x + threadIdx.x;
    if (i >= n) return;
    const uv4* hv = (const uv4*)hs_in;
    H8 p; p.u = hv[i];
    float2 a0 = __half22float2(p.h2[0]);
    float2 a1 = __half22float2(p.h2[1]);
    float2 a2 = __half22float2(p.h2[2]);
    float2 a3 = __half22float2(p.h2[3]);
    int s = __builtin_nontemporal_load(&rowptr[i]);
    int e = __builtin_nontemporal_load(&rowptr[i + 1]);
    for (int k = s; k < e; ++k) {
        int c = __builtin_nontemporal_load(&col[k]);
        H8 q; q.u = hv[c];
        float2 b0 = __half22float2(q.h2[0]);
        float2 b1 = __half22float2(q.h2[1]);
        float2 b2 = __half22float2(q.h2[2]);
        float2 b3 = __half22float2(q.h2[3]);
        a0.x += b0.x; a0.y += b0.y; a1.x += b1.x; a1.y += b1.y;
        a2.x += b2.x; a2.y += b2.y; a3.x += b3.x; a3.y += b3.y;
    }
    float d = __builtin_nontemporal_load(&dis[i]);
    fv4* gp = (fv4*)(g + (size_t)i * 8);
    fv4 o0 = {a0.x * d, a0.y * d, a1.x * d, a1.y * d};
    fv4 o1 = {a2.x * d, a2.y * d, a3.x * d, a3.y * d};
    __builtin_nontemporal_store(o0, gp);
    __builtin_nontemporal_store(o1, gp + 1);
}

// ---------------- final gather: out[i][:] = g[idx[i]][:] + b4 ----------------
__global__ void gather_out(const float* __restrict__ g, const int* __restrict__ idx,
                           const float* __restrict__ b, float* __restrict__ out, int B) {
    int t = blockIdx.x * blockDim.x + threadIdx.x;
    if (t >= B * 8) return;
    int i = t >> 3, j = t & 7;
    out[t] = g[(size_t)idx[i] * 8 + j] + b[j];
}

extern "C" void kernel_launch(void* const* d_in, const int* in_sizes, int n_in,
                              void* d_out, int out_size, void* d_ws, size_t ws_size,
                              hipStream_t stream) {
    const float* x   = (const float*)d_in[0];
    const int*   ei  = (const int*)d_in[1];
    const int*   idx = (const int*)d_in[2];
    const float* W1  = (const float*)d_in[3];
    const float* b1  = (const float*)d_in[4];
    const float* W2  = (const float*)d_in[5];
    const float* b2  = (const float*)d_in[6];
    const float* W3  = (const float*)d_in[7];
    const float* b3  = (const float*)d_in[8];
    const float* W4  = (const float*)d_in[9];
    const float* b4  = (const float*)d_in[10];

    const int n = in_sizes[0];      // 1,000,000 nodes (requires n <= 2^20 for packing)
    const int E = in_sizes[1] / 2;  // 10,000,000 edges
    const int B = in_sizes[2];      // 64 graphs

    const int* src = ei;
    const int* dst = ei + E;

    // workspace layout (int elements; all float4/uint4 regions 16B-aligned):
    //   rowptr: n+4 | col: E | dis: n | hs_a: 4n (fp16x8) | hs_b: 4n | g: 8n | small
    //   bucketData (E unsigned) aliases hs_b+g (consumed in build_csr before writes)
    size_t o_rowptr = 0;
    size_t o_col    = o_rowptr + ((size_t)n + 4);
    size_t o_dis    = o_col    + (size_t)E;
    size_t o_hsa    = o_dis    + (size_t)n;
    size_t o_hsb    = o_hsa    + (size_t)n * 4;
    size_t o_g      = o_hsb    + (size_t)n * 4;
    size_t o_small  = o_g      + (size_t)n * 8;

    int*      rowptr     = (int*)d_ws + o_rowptr;
    int*      col        = (int*)d_ws + o_col;
    float*    dis        = (float*)d_ws + o_dis;
    __half*   hs_a       = (__half*)((int*)d_ws + o_hsa);
    __half*   hs_b       = (__half*)((int*)d_ws + o_hsb);
    float*    g          = (float*)d_ws + o_g;
    int*      hist       = (int*)d_ws + o_small;
    int*      bucketOff  = hist + BN;
    int*      tails      = bucketOff + BN + 8;
    unsigned* bucketData = (unsigned*)hs_b;   // alias: 40 MB over hs_b(16MB)+g head

    const int NB = (n + BN - 1) / BN;           // coarse buckets (<= 1024)
    const int gn = (n + TPB - 1) / TPB;
    const int gs = (int)(((long)E + SCHUNK - 1) / SCHUNK);

    // ---- build CSR ----
    (void)hipMemsetAsync(hist, 0, BN * sizeof(int), stream);
    hist_buckets<<<1024, TPB, 0, stream>>>(dst, hist, E);
    scan1024<<<1, BN, 0, stream>>>(hist, bucketOff, tails, E);
    scatter_buckets<<<gs, TPB, 0, stream>>>(src, dst, tails, bucketData, E);
    build_csr<<<NB, TPB, 0, stream>>>(bucketData, bucketOff, rowptr, col, dis, n, E);

    // ---- 4 GCN layers: fused pull + node transform ----
    node_l1<<<gn, TPB, 0, stream>>>(x, W1, dis, hs_a, n);
    pull_mid<<<gn, TPB, 0, stream>>>(rowptr, col, dis, hs_a, b1, W2, hs_b, n);
    pull_mid<<<gn, TPB, 0, stream>>>(rowptr, col, dis, hs_b, b2, W3, hs_a, n);
    pull_mid<<<gn, TPB, 0, stream>>>(rowptr, col, dis, hs_a, b3, W4, hs_b, n);
    pull_last<<<gn, TPB, 0, stream>>>(rowptr, col, dis, hs_b, g, n);

    gather_out<<<(B * 8 + TPB - 1) / TPB, TPB, 0, stream>>>(g, idx, b4, (float*)d_out, B);
}

// Round 8
// 756.915 us; speedup vs baseline: 2.4389x; 1.7894x over previous
//
#include <hip/hip_runtime.h>
#include <hip/hip_fp16.h>

#define TPB 256
#define BN 1024           // nodes per coarse bucket (10 low bits)
#define ESTAGE 11264      // LDS staging capacity (mean 9766 + ~15 sigma)
#define SCHUNK 32768      // edges per block in scatter_buckets (32-edge/128B runs)

#define CAP2 409600       // frontier list caps (mean |T2|~85K, hard-bounded by sum of degs)
#define CAP3 40960
#define CAP4 4096

typedef unsigned int uv4 __attribute__((ext_vector_type(4)));

// ---------------- coarse histogram of dst >> 10 ----------------
__global__ void hist_buckets(const int* __restrict__ dst, int* __restrict__ hist, int nE) {
    __shared__ int lh[BN];
    for (int j = threadIdx.x; j < BN; j += blockDim.x) lh[j] = 0;
    __syncthreads();
    int stride = gridDim.x * blockDim.x;
    for (int e = blockIdx.x * blockDim.x + threadIdx.x; e < nE; e += stride)
        atomicAdd(&lh[dst[e] >> 10], 1);
    __syncthreads();
    for (int j = threadIdx.x; j < BN; j += blockDim.x)
        if (lh[j]) atomicAdd(&hist[j], lh[j]);
}

// ---------------- exclusive scan of 1024 bucket counts ----------------
__global__ void scan1024(const int* __restrict__ hist, int* __restrict__ bucketOff,
                         int* __restrict__ tails, int nE) {
    __shared__ int lds[BN];
    int t = threadIdx.x;
    int v = hist[t];
    lds[t] = v;
    __syncthreads();
    for (int off = 1; off < BN; off <<= 1) {
        int u = (t >= off) ? lds[t - off] : 0;
        __syncthreads();
        lds[t] += u;
        __syncthreads();
    }
    int excl = lds[t] - v;
    bucketOff[t] = excl;
    tails[t] = excl;
    if (t == BN - 1) bucketOff[BN] = lds[BN - 1];   // == nE
}

// ---------------- scatter edges into coarse buckets (two-pass, block-aggregated) ----------
// payload: (dstLow10 << 20) | src   (requires n <= 2^20)
__global__ void scatter_buckets(const int* __restrict__ src, const int* __restrict__ dst,
                                int* __restrict__ tails, unsigned* __restrict__ bucketData,
                                int nE) {
    __shared__ int hist[BN];
    __shared__ int cbase[BN];
    int t = threadIdx.x;
    long base = (long)blockIdx.x * SCHUNK;
    int m = (int)(((long)nE - base < SCHUNK) ? (nE - base) : SCHUNK);
    for (int j = t; j < BN; j += TPB) hist[j] = 0;
    __syncthreads();
    // pass 1: count
    for (int k = t; k < m; k += TPB)
        atomicAdd(&hist[dst[base + k] >> 10], 1);
    __syncthreads();
    // reserve contiguous runs per bucket
    for (int j = t; j < BN; j += TPB) {
        int h = hist[j];
        cbase[j] = h ? atomicAdd(&tails[j], h) : 0;
    }
    __syncthreads();
    for (int j = t; j < BN; j += TPB) hist[j] = 0;   // reuse as cursor
    __syncthreads();
    // pass 2: scatter (runs avg 32 edges = 128 B per bucket per block)
    for (int k = t; k < m; k += TPB) {
        int d = dst[base + k];
        int b = d >> 10;
        int r = atomicAdd(&hist[b], 1);
        bucketData[cbase[b] + r] = ((unsigned)(d & (BN - 1)) << 20) | (unsigned)src[base + k];
    }
}

// ---------------- per-bucket: degrees -> dis, rowptr, row-grouped + src-sorted col ------
// NOTE: col ALIASES bucketData. Safe: block reads bucketData[e0,e1) fully
// (count pass + LDS scatter pass) before writing col[e0,e1) from LDS.
__global__ __launch_bounds__(TPB) void build_csr(
        const unsigned* __restrict__ bucketData, const int* __restrict__ bucketOff,
        int* __restrict__ rowptr, int* __restrict__ col,
        float* __restrict__ dis, int n, int nE) {
    __shared__ unsigned sorted[ESTAGE];   // 44 KB
    __shared__ int cnt[BN];               // 4 KB
    __shared__ int partial[TPB];
    int b = blockIdx.x;
    int t = threadIdx.x;
    int e0 = bucketOff[b], e1 = bucketOff[b + 1];
    int m = e1 - e0;
    for (int j = t; j < BN; j += TPB) cnt[j] = 0;
    __syncthreads();
    // count pass (global read #1)
    for (int k = e0 + t; k < e1; k += TPB)
        atomicAdd(&cnt[bucketData[k] >> 20], 1);
    __syncthreads();
    // dis from degree
    int base0 = b << 10;
    for (int j = t; j < BN; j += TPB) {
        int node = base0 + j;
        if (node < n) dis[node] = rsqrtf((float)cnt[j] + 1.0f);
    }
    // exclusive scan of cnt[0..1023]
    int tb = t * 4;
    int loc[4];
    int s = 0;
#pragma unroll
    for (int j = 0; j < 4; ++j) { loc[j] = s; s += cnt[tb + j]; }
    partial[t] = s;
    __syncthreads();
    for (int off = 1; off < TPB; off <<= 1) {
        int u = (t >= off) ? partial[t - off] : 0;
        __syncthreads();
        partial[t] += u;
        __syncthreads();
    }
    int pbase = (t > 0) ? partial[t - 1] : 0;
    __syncthreads();
#pragma unroll
    for (int j = 0; j < 4; ++j) {
        int node = base0 + tb + j;
        int lb = pbase + loc[j];
        cnt[tb + j] = lb;                  // local row start (cursor)
        if (node < n) rowptr[node] = e0 + lb;
    }
    if (b == 0 && t == 0) rowptr[n] = nE;
    __syncthreads();
    if (m <= ESTAGE) {
        // scatter into LDS, row-grouped (global read #2 — last read of bucketData)
        for (int k = e0 + t; k < e1; k += TPB) {
            unsigned p = bucketData[k];
            int pos = atomicAdd(&cnt[p >> 20], 1);
            sorted[pos] = p;
        }
        __syncthreads();
        // insertion-sort each row in LDS (dst constant in row => sorts by src)
        for (int j = t; j < BN; j += TPB) {
            int rs = (j == 0) ? 0 : cnt[j - 1];
            int re = cnt[j];
            for (int a = rs + 1; a < re; ++a) {
                unsigned v = sorted[a];
                int c = a - 1;
                while (c >= rs && sorted[c] > v) { sorted[c + 1] = sorted[c]; --c; }
                sorted[c + 1] = v;
            }
        }
        __syncthreads();
        // coalesced write-out (col aliases bucketData — all reads done)
        for (int k = t; k < m; k += TPB)
            col[e0 + k] = (int)(sorted[k] & 0xFFFFFu);
    } else {
        // fallback: P ~ 0 (15 sigma). Stage via LDS in chunks to respect aliasing.
        for (int k0 = e0; k0 < e1; k0 += ESTAGE) {
            int mm = min(ESTAGE, e1 - k0);
            for (int k = t; k < mm; k += TPB) sorted[k] = bucketData[k0 + k];
            __syncthreads();
            for (int k = t; k < mm; k += TPB) {
                unsigned p = sorted[k];
                int pos = atomicAdd(&cnt[p >> 20], 1);
                col[e0 + pos] = (int)(p & 0xFFFFFu);
            }
            __syncthreads();
        }
        for (int j = t; j < BN; j += TPB) {
            int rs = e0 + ((j == 0) ? 0 : cnt[j - 1]);
            int re = e0 + cnt[j];
            for (int a = rs + 1; a < re; ++a) {
                int v = col[a];
                int c = a - 1;
                while (c >= rs && col[c] > v) { col[c + 1] = col[c]; --c; }
                col[c + 1] = v;
            }
        }
    }
}

// ---------------- frontier expand: out = unique(seeds ∪ N_in(seeds)) ----------------
__global__ void expand(const int* __restrict__ seeds, const int* __restrict__ cntPtr,
                       int staticCnt,
                       const int* __restrict__ rowptr, const int* __restrict__ col,
                       int* __restrict__ flag, int tag,
                       int* __restrict__ outList, int* __restrict__ outCnt) {
    int cnt = cntPtr ? *cntPtr : staticCnt;
    int tid = blockIdx.x * blockDim.x + threadIdx.x;
    if (tid >= cnt) return;
    int u = seeds[tid];
    if (atomicExch(&flag[u], tag) != tag)
        outList[atomicAdd(outCnt, 1)] = u;
    int s = rowptr[u], e = rowptr[u + 1];
    for (int k = s; k < e; ++k) {
        int v = col[k];
        if (atomicExch(&flag[v], tag) != tag)
            outList[atomicAdd(outCnt, 1)] = v;
    }
}

union H8 { uv4 u; __half2 h2[4]; };

// ---------------- layer 1 node kernel (all nodes): hs = (x*W1)*dis  (fp16x8) --------
__global__ void node_l1(const float* __restrict__ x, const float* __restrict__ W1,
                        const float* __restrict__ dis, __half* __restrict__ hs, int n) {
    int i = blockIdx.x * blockDim.x + threadIdx.x;
    if (i >= n) return;
    float xd = x[i] * dis[i];
    float4 w0 = ((const float4*)W1)[0];
    float4 w1 = ((const float4*)W1)[1];
    H8 o;
    o.h2[0] = __floats2half2_rn(xd * w0.x, xd * w0.y);
    o.h2[1] = __floats2half2_rn(xd * w0.z, xd * w0.w);
    o.h2[2] = __floats2half2_rn(xd * w1.x, xd * w1.y);
    o.h2[3] = __floats2half2_rn(xd * w1.z, xd * w1.w);
    ((uv4*)hs)[i] = o.u;
}

// ---------------- fused pull + node transform, over a frontier list ----------------
// for i in list: g = dis[i]*(sum hs_in[row(i)] + hs_in[i]); t = relu(g+b);
//                hs_out[i] = (t @ W) * dis[i]
__global__ void pull_list(const int* __restrict__ list, const int* __restrict__ cntPtr,
                          const int* __restrict__ rowptr, const int* __restrict__ col,
                          const float* __restrict__ dis, const __half* __restrict__ hs_in,
                          const float* __restrict__ bias, const float* __restrict__ W,
                          __half* __restrict__ hs_out) {
    int tid = blockIdx.x * blockDim.x + threadIdx.x;
    if (tid >= *cntPtr) return;
    int i = list[tid];
    const uv4* hv = (const uv4*)hs_in;
    H8 p; p.u = hv[i];                       // self term
    float2 a0 = __half22float2(p.h2[0]);
    float2 a1 = __half22float2(p.h2[1]);
    float2 a2 = __half22float2(p.h2[2]);
    float2 a3 = __half22float2(p.h2[3]);
    int s = rowptr[i], e = rowptr[i + 1];
    for (int k = s; k < e; ++k) {
        H8 q; q.u = hv[col[k]];
        float2 b0 = __half22float2(q.h2[0]);
        float2 b1 = __half22float2(q.h2[1]);
        float2 b2 = __half22float2(q.h2[2]);
        float2 b3 = __half22float2(q.h2[3]);
        a0.x += b0.x; a0.y += b0.y; a1.x += b1.x; a1.y += b1.y;
        a2.x += b2.x; a2.y += b2.y; a3.x += b3.x; a3.y += b3.y;
    }
    float d = dis[i];
    float t[8] = {a0.x * d, a0.y * d, a1.x * d, a1.y * d,
                  a2.x * d, a2.y * d, a3.x * d, a3.y * d};
#pragma unroll
    for (int k = 0; k < 8; ++k) {
        float v = t[k] + bias[k];
        t[k] = v > 0.0f ? v : 0.0f;
    }
    float h[8];
#pragma unroll
    for (int j = 0; j < 8; ++j) {
        float acc = 0.0f;
#pragma unroll
        for (int k = 0; k < 8; ++k) acc += t[k] * W[k * 8 + j];
        h[j] = acc * d;
    }
    H8 o;
    o.h2[0] = __floats2half2_rn(h[0], h[1]);
    o.h2[1] = __floats2half2_rn(h[2], h[3]);
    o.h2[2] = __floats2half2_rn(h[4], h[5]);
    o.h2[3] = __floats2half2_rn(h[6], h[7]);
    ((uv4*)hs_out)[i] = o.u;
}

// ---------------- final: out[t][:] = dis*(sum+self) + b4, for the 64 idx nodes ------
__global__ void pull_final(const int* __restrict__ idx, int B,
                           const int* __restrict__ rowptr, const int* __restrict__ col,
                           const float* __restrict__ dis, const __half* __restrict__ hs_in,
                           const float* __restrict__ b4, float* __restrict__ out) {
    int tnum = blockIdx.x * blockDim.x + threadIdx.x;
    if (tnum >= B) return;
    int i = idx[tnum];
    const uv4* hv = (const uv4*)hs_in;
    H8 p; p.u = hv[i];
    float2 a0 = __half22float2(p.h2[0]);
    float2 a1 = __half22float2(p.h2[1]);
    float2 a2 = __half22float2(p.h2[2]);
    float2 a3 = __half22float2(p.h2[3]);
    int s = rowptr[i], e = rowptr[i + 1];
    for (int k = s; k < e; ++k) {
        H8 q; q.u = hv[col[k]];
        float2 b0 = __half22float2(q.h2[0]);
        float2 b1 = __half22float2(q.h2[1]);
        float2 b2 = __half22float2(q.h2[2]);
        float2 b3 = __half22float2(q.h2[3]);
        a0.x += b0.x; a0.y += b0.y; a1.x += b1.x; a1.y += b1.y;
        a2.x += b2.x; a2.y += b2.y; a3.x += b3.x; a3.y += b3.y;
    }
    float d = dis[i];
    float* op = out + (size_t)tnum * 8;
    op[0] = a0.x * d + b4[0]; op[1] = a0.y * d + b4[1];
    op[2] = a1.x * d + b4[2]; op[3] = a1.y * d + b4[3];
    op[4] = a2.x * d + b4[4]; op[5] = a2.y * d + b4[5];
    op[6] = a3.x * d + b4[6]; op[7] = a3.y * d + b4[7];
}

extern "C" void kernel_launch(void* const* d_in, const int* in_sizes, int n_in,
                              void* d_out, int out_size, void* d_ws, size_t ws_size,
                              hipStream_t stream) {
    const float* x   = (const float*)d_in[0];
    const int*   ei  = (const int*)d_in[1];
    const int*   idx = (const int*)d_in[2];
    const float* W1  = (const float*)d_in[3];
    const float* b1  = (const float*)d_in[4];
    const float* W2  = (const float*)d_in[5];
    const float* b2  = (const float*)d_in[6];
    const float* W3  = (const float*)d_in[7];
    const float* b3  = (const float*)d_in[8];
    const float* W4  = (const float*)d_in[9];
    const float* b4  = (const float*)d_in[10];

    const int n = in_sizes[0];      // 1,000,000 nodes (requires n <= 2^20 for packing)
    const int E = in_sizes[1] / 2;  // 10,000,000 edges
    const int B = in_sizes[2];      // 64 graphs

    const int* src = ei;
    const int* dst = ei + E;

    // workspace layout (int elements; all 16B-aligned):
    //   rowptr: n+4 | colData: E (col ALIASES bucketData) | dis: n |
    //   A: 4n (fp16x8) | Bf: 4n | flag: n | l2: CAP2 | l3: CAP3 | l4: CAP4 | small
    size_t o_rowptr = 0;
    size_t o_col    = o_rowptr + ((size_t)n + 4);
    size_t o_dis    = o_col    + (size_t)E;
    size_t o_A      = o_dis    + (size_t)n;
    size_t o_B      = o_A      + (size_t)n * 4;
    size_t o_flag   = o_B      + (size_t)n * 4;
    size_t o_l2     = o_flag   + (size_t)n;
    size_t o_l3     = o_l2     + CAP2;
    size_t o_l4     = o_l3     + CAP3;
    size_t o_small  = o_l4     + CAP4;

    int*      rowptr     = (int*)d_ws + o_rowptr;
    int*      col        = (int*)d_ws + o_col;
    float*    dis        = (float*)d_ws + o_dis;
    __half*   hsA        = (__half*)((int*)d_ws + o_A);
    __half*   hsB        = (__half*)((int*)d_ws + o_B);
    int*      flag       = (int*)d_ws + o_flag;
    int*      l2         = (int*)d_ws + o_l2;
    int*      l3         = (int*)d_ws + o_l3;
    int*      l4         = (int*)d_ws + o_l4;
    int*      hist       = (int*)d_ws + o_small;
    int*      bucketOff  = hist + BN;
    int*      tails      = bucketOff + BN + 8;
    int*      cnts       = tails + BN;        // cnt4, cnt3, cnt2
    unsigned* bucketData = (unsigned*)col;    // alias (block-local read-then-write)

    const int NB = (n + BN - 1) / BN;
    const int gn = (n + TPB - 1) / TPB;
    const int gs = (int)(((long)E + SCHUNK - 1) / SCHUNK);

    // ---- zero init (per call; d_ws is re-poisoned before every launch) ----
    (void)hipMemsetAsync(hist, 0, BN * sizeof(int), stream);
    (void)hipMemsetAsync(cnts, 0, 8 * sizeof(int), stream);
    (void)hipMemsetAsync(flag, 0, (size_t)n * sizeof(int), stream);

    // ---- build CSR (sorted rows) ----
    hist_buckets<<<1024, TPB, 0, stream>>>(dst, hist, E);
    scan1024<<<1, BN, 0, stream>>>(hist, bucketOff, tails, E);
    scatter_buckets<<<gs, TPB, 0, stream>>>(src, dst, tails, bucketData, E);
    build_csr<<<NB, TPB, 0, stream>>>(bucketData, bucketOff, rowptr, col, dis, n, E);

    // ---- dependency-cone frontiers: T4 = idx∪N(idx), T3 = T4∪N(T4), T2 = T3∪N(T3) ----
    expand<<<1, 64, 0, stream>>>(idx, nullptr, B, rowptr, col, flag, 1, l4, &cnts[0]);
    expand<<<CAP4 / TPB, TPB, 0, stream>>>(l4, &cnts[0], 0, rowptr, col, flag, 2, l3, &cnts[1]);
    expand<<<CAP3 / TPB, TPB, 0, stream>>>(l3, &cnts[1], 0, rowptr, col, flag, 3, l2, &cnts[2]);

    // ---- layers: hs1 everywhere (cheap), then pulls restricted to the cone ----
    node_l1<<<gn, TPB, 0, stream>>>(x, W1, dis, hsA, n);
    pull_list<<<CAP2 / TPB, TPB, 0, stream>>>(l2, &cnts[2], rowptr, col, dis, hsA, b1, W2, hsB);
    pull_list<<<CAP3 / TPB, TPB, 0, stream>>>(l3, &cnts[1], rowptr, col, dis, hsB, b2, W3, hsA);
    pull_list<<<CAP4 / TPB, TPB, 0, stream>>>(l4, &cnts[0], rowptr, col, dis, hsA, b3, W4, hsB);
    pull_final<<<1, 64, 0, stream>>>(idx, B, rowptr, col, dis, hsB, b4, (float*)d_out);
}